// Round 8
// baseline (229.648 us; speedup 1.0000x reference)
//
#include <hip/hip_runtime.h>
#include <math.h>

// Problem constants (B=8, T=1024, C=32, F=256, D=128, K=512)
#define N_POS 8192
#define D_DIM 128
#define K_DIM 512
#define C_DIM 32
#define F_DIM 256

#define PT 64            // positions per NN tile
#define KW 128           // codewords per NN tile
#define NKT 4            // k-tiles
#define XG_BLOCKS 256    // 32 bt-rows each (R5/R7-proven shape) -- FIRST in grid
#define NN_BLOCKS 512    // 128 ptiles x 4 ktiles (R6-proven tile, VGPR=120)
#define GRID (XG_BLOCKS + NN_BLOCKS)
#define NCOPY 8          // striped g_rec/S copies (atomic contention / 8)
#define GCOLS 8448       // 32*256 g_rec + 256 S

// zeroed-ws layout (floats): [0..7] accum (0=sse_rec,1=dsum,2=sse_mem),
// [8..135] ptile counters (128), [136] gcnt, [137..143] pad,
// [144..144+8*8448) g_rec/S copies.  pd64 (u64[4*8192]) follows, un-zeroed.
#define GC_OFF 144
#define ZWS_FLOATS (GC_OFF + NCOPY * GCOLS)    // 67728

// ---------------------------------------------------------------- reductions
__device__ __forceinline__ float block_reduce_256(float v) {
    __shared__ float sbuf[4];
    __syncthreads();
#pragma unroll
    for (int off = 32; off > 0; off >>= 1) v += __shfl_down(v, off);
    const int lane = threadIdx.x & 63;
    const int w    = threadIdx.x >> 6;
    if (lane == 0) sbuf[w] = v;
    __syncthreads();
    return (threadIdx.x == 0) ? (sbuf[0] + sbuf[1] + sbuf[2] + sbuf[3]) : 0.f;
}

__global__ __launch_bounds__(256, 2)
void fused_all(const float* __restrict__ H, const float* __restrict__ M,
               const float* __restrict__ Hdec, const float* __restrict__ W,
               const float* __restrict__ X, const float* __restrict__ w_d,
               float* __restrict__ zws,
               unsigned long long* __restrict__ pd64,
               float* __restrict__ out) {
    // NN: hT 8K + mT 16K + red64 8K = 32K.  XG: Wl 33280 + El 4096 = 37376.
    __shared__ __align__(16) char smem[37376];
    float* accum = zws;
    unsigned int* ptile_cnt = (unsigned int*)(zws + 8);
    unsigned int* gcnt      = (unsigned int*)(zws + 136);
    float* gcopy = zws + GC_OFF;
    const int tid = threadIdx.x;

    if (blockIdx.x >= XG_BLOCKS) {
        // ======= NN: 64 pos x 128 k tile, 4x8 acc (R6-proven, no spill) =======
        float* hT = (float*)smem;                                   // [32][64]
        float* mT = hT + 2048;                                      // [32][128]
        unsigned long long* red64 = (unsigned long long*)(smem + 24576); // [16][64]

        const int nb    = blockIdx.x - XG_BLOCKS;
        const int ptile = nb >> 2;               // 0..127
        const int ktile = nb & 3;                // 0..3
        const int pos0  = ptile * PT;            // 64-aligned, never crosses b
        const int b     = pos0 >> 10;
        const int t0    = pos0 & 1023;
        const int k0    = ktile * KW;
        const float* Hb = H + (b << 17) + t0;

        const int p4 = (tid & 15) << 2;          // pos quad 0..60
        const int q8 = (tid >> 4) << 3;          // k octet 0..120

        float acc[4][8];
#pragma unroll
        for (int i = 0; i < 4; ++i)
#pragma unroll
            for (int j = 0; j < 8; ++j) acc[i][j] = 0.f;

        for (int ch = 0; ch < 4; ++ch) {         // 32-d chunks
            const int d0 = ch << 5;
            __syncthreads();
            {
                int idx = tid * 4;               // hT: 2048 floats
#pragma unroll
                for (int it = 0; it < 2; ++it, idx += 1024) {
                    const int d = idx >> 6, cc = idx & 63;
                    *(float4*)(hT + idx) =
                        *(const float4*)(Hb + ((size_t)(d0 + d) << 10) + cc);
                }
                idx = tid * 4;                   // mT: 4096 floats
#pragma unroll
                for (int it = 0; it < 4; ++it, idx += 1024) {
                    const int d = idx >> 7, cc = idx & 127;
                    *(float4*)(mT + idx) =
                        *(const float4*)(M + (size_t)(d0 + d) * K_DIM + k0 + cc);
                }
            }
            __syncthreads();
#pragma unroll 2
            for (int d = 0; d < 32; ++d) {
                const float4 h4 = *(const float4*)(hT + (d << 6) + p4);
                const float4 m0 = *(const float4*)(mT + (d << 7) + q8);
                const float4 m1 = *(const float4*)(mT + (d << 7) + q8 + 4);
                const float hh[4] = {h4.x, h4.y, h4.z, h4.w};
                const float mm[8] = {m0.x, m0.y, m0.z, m0.w, m1.x, m1.y, m1.z, m1.w};
#pragma unroll
                for (int i = 0; i < 4; ++i)
#pragma unroll
                    for (int j = 0; j < 8; ++j)
                        acc[i][j] += fabsf(hh[i] - mm[j]);
            }
        }

        // per-thread argmin over 8 ks (j ascending, strict < -> lowest k on tie);
        // packed u64 (dist_bits, k): u64-min == lexicographic (dist, k)
#pragma unroll
        for (int i = 0; i < 4; ++i) {
            float bd = acc[i][0];
            int   bj = 0;
#pragma unroll
            for (int j = 1; j < 8; ++j)
                if (acc[i][j] < bd) { bd = acc[i][j]; bj = j; }
            red64[(tid >> 4) * PT + p4 + i] =
                ((unsigned long long)__float_as_uint(bd) << 32)
                | (unsigned int)(k0 + q8 + bj);
        }
        __syncthreads();
        if (tid < PT) {
            unsigned long long best = red64[tid];
#pragma unroll
            for (int g = 1; g < 16; ++g) {
                const unsigned long long w = red64[g * PT + tid];
                if (w < best) best = w;
            }
            pd64[ktile * N_POS + pos0 + tid] = best;
        }
        __threadfence();     // release pd64 slice device-wide
        __syncthreads();
        __shared__ int lastp;
        if (tid == 0) lastp = (atomicAdd(&ptile_cnt[ptile], 1u) == 3u);
        __syncthreads();
        if (lastp) {
            __threadfence();                     // acquire other ktiles' pd64
            int* bi_l = (int*)smem;              // hT region is dead
            if (tid < PT) {
                unsigned long long best = ~0ull;
#pragma unroll
                for (int p = 0; p < NKT; ++p) {
                    const unsigned long long w = __hip_atomic_load(
                        pd64 + p * N_POS + pos0 + tid,
                        __ATOMIC_RELAXED, __HIP_MEMORY_SCOPE_AGENT);
                    if (w < best) best = w;
                }
                bi_l[tid] = (int)(unsigned int)(best & 0xffffffffu);
            }
            __syncthreads();
            const int pl = tid & 63;             // position
            const int dh = tid >> 6;             // 0..3, 32 d each
            const int bi = bi_l[pl];
            const float* Hp = H + (b << 17) + t0 + pl;
            float s = 0.f;
#pragma unroll 8
            for (int d = dh * 32; d < dh * 32 + 32; ++d) {
                const float e = Hp[(size_t)d << 10] - M[(size_t)d * K_DIM + bi];
                s += e * e;
            }
            const float r = block_reduce_256(s);
            if (tid == 0) atomicAdd(accum + 2, r);
        }
    } else {
        // ========== XG: xhat + E + loss_rec/disc + grec partials (32 rows) =====
        float* Wl = (float*)smem;                // [32][260]
        float* El = Wl + C_DIM * 260;            // [32][32]
        const int xb  = blockIdx.x;              // 0..255
        const int bt0 = xb << 5;

#pragma unroll
        for (int it = 0; it < 8; ++it) {         // stage W
            const int i = it * 1024 + tid * 4;
            const float4 v = *(const float4*)(W + i);
            *(float4*)(Wl + (i >> 8) * 260 + (i & 255)) = v;
        }
        __syncthreads();

        const int c  = tid & 31;
        const int rg = tid >> 5;                 // 0..7
        const int r0 = bt0 + rg, r1 = r0 + 8, r2 = r0 + 16, r3 = r0 + 24;

        float a0 = 0.f, a1 = 0.f, a2 = 0.f, a3 = 0.f;
#pragma unroll 4
        for (int f0 = 0; f0 < F_DIM; f0 += 4) {
            const float4 w4 = *(const float4*)(Wl + c * 260 + f0);
            const float4 h0 = *(const float4*)(Hdec + (size_t)r0 * F_DIM + f0);
            const float4 h1 = *(const float4*)(Hdec + (size_t)r1 * F_DIM + f0);
            const float4 h2 = *(const float4*)(Hdec + (size_t)r2 * F_DIM + f0);
            const float4 h3 = *(const float4*)(Hdec + (size_t)r3 * F_DIM + f0);
            a0 += h0.x * w4.x + h0.y * w4.y + h0.z * w4.z + h0.w * w4.w;
            a1 += h1.x * w4.x + h1.y * w4.y + h1.z * w4.z + h1.w * w4.w;
            a2 += h2.x * w4.x + h2.y * w4.y + h2.z * w4.z + h2.w * w4.w;
            a3 += h3.x * w4.x + h3.y * w4.y + h3.z * w4.z + h3.w * w4.w;
        }

        const float wd = w_d[c];
        const float e0 = a0 - X[(size_t)r0 * C_DIM + c];
        const float e1 = a1 - X[(size_t)r1 * C_DIM + c];
        const float e2 = a2 - X[(size_t)r2 * C_DIM + c];
        const float e3 = a3 - X[(size_t)r3 * C_DIM + c];
        El[(rg)      * C_DIM + c] = e0;
        El[(rg + 8)  * C_DIM + c] = e1;
        El[(rg + 16) * C_DIM + c] = e2;
        El[(rg + 24) * C_DIM + c] = e3;
        const float sse = e0 * e0 + e1 * e1 + e2 * e2 + e3 * e3;
        const float dp  = (a0 + a1 + a2 + a3) * wd;
        const float rA = block_reduce_256(sse);
        if (tid == 0) atomicAdd(accum + 0, rA);
        const float rB = block_reduce_256(dp);
        if (tid == 0) atomicAdd(accum + 1, rB);
        __syncthreads();                         // El fully visible

        // grec: thread = f; E rows broadcast from LDS
        float gacc[C_DIM];
#pragma unroll
        for (int cc = 0; cc < C_DIM; ++cc) gacc[cc] = 0.f;
        float sf = 0.f;
#pragma unroll 1
        for (int i = 0; i < 32; ++i) {
            const float hd = Hdec[(size_t)(bt0 + i) * F_DIM + tid];   // coalesced
            sf += hd;
#pragma unroll
            for (int c4 = 0; c4 < 8; ++c4) {
                const float4 e4 = *(const float4*)(El + i * C_DIM + c4 * 4);
                gacc[c4 * 4 + 0] += e4.x * hd;
                gacc[c4 * 4 + 1] += e4.y * hd;
                gacc[c4 * 4 + 2] += e4.z * hd;
                gacc[c4 * 4 + 3] += e4.w * hd;
            }
        }
        float* gc = gcopy + (size_t)(xb & (NCOPY - 1)) * GCOLS;
#pragma unroll 1
        for (int cc = 0; cc < C_DIM; ++cc)
            atomicAdd(&gc[cc * F_DIM + tid], gacc[cc]);
        atomicAdd(&gc[8192 + tid], sf);
    }

    // ============== common epilogue: last block assembles the scalar ==========
    __shared__ int lastg;
    __threadfence();
    __syncthreads();
    if (tid == 0) lastg = (atomicAdd(gcnt, 1u) == (unsigned)(GRID - 1));
    __syncthreads();
    if (lastg) {
        __threadfence();                          // acquire all copies/accum
        float g2 = 0.f;
        for (int i = tid; i < 8192; i += 256) {
            float v = 0.f;
#pragma unroll
            for (int cp = 0; cp < NCOPY; ++cp)
                v += __hip_atomic_load(gcopy + cp * GCOLS + i,
                                       __ATOMIC_RELAXED, __HIP_MEMORY_SCOPE_AGENT);
            g2 += v * v;
        }
        const float rg2 = block_reduce_256(g2);
        float vS = 0.f;
#pragma unroll
        for (int cp = 0; cp < NCOPY; ++cp)
            vS += __hip_atomic_load(gcopy + cp * GCOLS + 8192 + tid,
                                    __ATOMIC_RELAXED, __HIP_MEMORY_SCOPE_AGENT);
        const float rs2 = block_reduce_256(vS * vS);
        float wd2 = (tid < C_DIM) ? w_d[tid] * w_d[tid] : 0.f;
        if (tid < 64) {
#pragma unroll
            for (int off = 32; off > 0; off >>= 1) wd2 += __shfl_down(wd2, off);
        }
        if (tid == 0) {
            const float sse_rec = atomicAdd(accum + 0, 0.f);
            const float dsum    = atomicAdd(accum + 1, 0.f);
            const float sse_mem = atomicAdd(accum + 2, 0.f);
            const float loss_rec = sse_rec / 262144.f;         // /(B*T*C)
            const float loss_d   = -dsum / 8192.f;             // -mean over B*T
            const float loss_m   = 2.f * sse_mem / 1048576.f;  // 2*SSE/(B*D*T)
            const float ngrec    = (2.f / 262144.f) * sqrtf(rg2);
            const float ngd      = sqrtf(wd2 * rs2) / 8192.f;
            const float lmbda    = ngrec / (ngd + 1e-6f);
            out[0] = loss_rec + loss_m + lmbda * loss_d;       // ALPHA = 1
        }
    }
}

// ---------------------------------------------------------------- launcher
extern "C" void kernel_launch(void* const* d_in, const int* in_sizes, int n_in,
                              void* d_out, int out_size, void* d_ws, size_t ws_size,
                              hipStream_t stream) {
    const float* X    = (const float*)d_in[0];   // [8,1024,32]
    const float* H    = (const float*)d_in[1];   // [8,128,1024]
    const float* M    = (const float*)d_in[2];   // [128,512]
    const float* Hdec = (const float*)d_in[3];   // [8,1024,256]
    const float* W    = (const float*)d_in[4];   // [32,256]
    const float* w_d  = (const float*)d_in[5];   // [32]

    float* zws = (float*)d_ws;
    unsigned long long* pd64 = (unsigned long long*)(zws + ZWS_FLOATS); // 8B-aligned

    hipMemsetAsync(zws, 0, ZWS_FLOATS * sizeof(float), stream);
    fused_all<<<GRID, 256, 0, stream>>>(H, M, Hdec, W, X, w_d,
                                        zws, pd64, (float*)d_out);
}

// Round 9
// 182.730 us; speedup vs baseline: 1.2568x; 1.2568x over previous
//
#include <hip/hip_runtime.h>
#include <math.h>

// Problem constants (B=8, T=1024, C=32, F=256, D=128, K=512)
#define N_POS 8192
#define D_DIM 128
#define K_DIM 512
#define C_DIM 32
#define F_DIM 256

#define PT 64            // positions per NN tile
#define KW 128           // codewords per NN tile
#define NKT 4            // k-tiles
#define NN_BLOCKS 512    // 128 ptiles x 4 ktiles
#define TAIL_BLOCKS 512  // 256 merge+SSE + 256 XG
#define NCOPY 8          // striped g_rec/S copies
#define GCOLS 8448       // 32*256 g_rec + 256 S

// zeroed-ws layout (floats): [0..7] accum (0=sse_rec,1=dsum,2=sse_mem),
// [8] gcnt, [9..15] pad, [16..16+8*8448) g_rec/S copies.
// pd64 (u64[4*8192]) follows, un-zeroed.
#define GC_OFF 16
#define ZWS_FLOATS (GC_OFF + NCOPY * GCOLS)    // 67600

// ---------------------------------------------------------------- reductions
__device__ __forceinline__ float block_reduce_256(float v) {
    __shared__ float sbuf[4];
    __syncthreads();
#pragma unroll
    for (int off = 32; off > 0; off >>= 1) v += __shfl_down(v, off);
    const int lane = threadIdx.x & 63;
    const int w    = threadIdx.x >> 6;
    if (lane == 0) sbuf[w] = v;
    __syncthreads();
    return (threadIdx.x == 0) ? (sbuf[0] + sbuf[1] + sbuf[2] + sbuf[3]) : 0.f;
}

// ============ kernel 1: NN search, DEDICATED (isolated reg allocation) ======
// 64 pos x 128 k tile, 4x8 acc (32 regs — the shape that allocated VGPR=120
// in R6). Writes packed u64 (dist_bits<<32 | k); u64-min == lexicographic
// (dist, k) == reference first-min tie-break.
__global__ __launch_bounds__(256, 2)
void nn_kernel(const float* __restrict__ H, const float* __restrict__ M,
               unsigned long long* __restrict__ pd64) {
    __shared__ __align__(16) char smem[32768];
    float* hT = (float*)smem;                                   // [32][64]
    float* mT = hT + 2048;                                      // [32][128]
    unsigned long long* red64 = (unsigned long long*)(smem + 24576); // [16][64]
    const int tid = threadIdx.x;

    const int ptile = blockIdx.x >> 2;       // 0..127
    const int ktile = blockIdx.x & 3;        // 0..3
    const int pos0  = ptile * PT;            // 64-aligned, never crosses b
    const int b     = pos0 >> 10;
    const int t0    = pos0 & 1023;
    const int k0    = ktile * KW;
    const float* Hb = H + (b << 17) + t0;

    const int p4 = (tid & 15) << 2;          // pos quad 0..60
    const int q8 = (tid >> 4) << 3;          // k octet 0..120

    float acc[4][8];
#pragma unroll
    for (int i = 0; i < 4; ++i)
#pragma unroll
        for (int j = 0; j < 8; ++j) acc[i][j] = 0.f;

    for (int ch = 0; ch < 4; ++ch) {         // 32-d chunks
        const int d0 = ch << 5;
        __syncthreads();
        {
            int idx = tid * 4;               // hT: 2048 floats
#pragma unroll
            for (int it = 0; it < 2; ++it, idx += 1024) {
                const int d = idx >> 6, cc = idx & 63;
                *(float4*)(hT + idx) =
                    *(const float4*)(Hb + ((size_t)(d0 + d) << 10) + cc);
            }
            idx = tid * 4;                   // mT: 4096 floats
#pragma unroll
            for (int it = 0; it < 4; ++it, idx += 1024) {
                const int d = idx >> 7, cc = idx & 127;
                *(float4*)(mT + idx) =
                    *(const float4*)(M + (size_t)(d0 + d) * K_DIM + k0 + cc);
            }
        }
        __syncthreads();
#pragma unroll 2
        for (int d = 0; d < 32; ++d) {
            const float4 h4 = *(const float4*)(hT + (d << 6) + p4);
            const float4 m0 = *(const float4*)(mT + (d << 7) + q8);
            const float4 m1 = *(const float4*)(mT + (d << 7) + q8 + 4);
            const float hh[4] = {h4.x, h4.y, h4.z, h4.w};
            const float mm[8] = {m0.x, m0.y, m0.z, m0.w, m1.x, m1.y, m1.z, m1.w};
#pragma unroll
            for (int i = 0; i < 4; ++i)
#pragma unroll
                for (int j = 0; j < 8; ++j)
                    acc[i][j] += fabsf(hh[i] - mm[j]);
        }
    }

    // per-thread argmin over 8 ks (j ascending, strict < -> lowest k on tie)
#pragma unroll
    for (int i = 0; i < 4; ++i) {
        float bd = acc[i][0];
        int   bj = 0;
#pragma unroll
        for (int j = 1; j < 8; ++j)
            if (acc[i][j] < bd) { bd = acc[i][j]; bj = j; }
        red64[(tid >> 4) * PT + p4 + i] =
            ((unsigned long long)__float_as_uint(bd) << 32)
            | (unsigned int)(k0 + q8 + bj);
    }
    __syncthreads();
    if (tid < PT) {
        unsigned long long best = red64[tid];
#pragma unroll
        for (int g = 1; g < 16; ++g) {
            const unsigned long long w = red64[g * PT + tid];
            if (w < best) best = w;
        }
        pd64[ktile * N_POS + pos0 + tid] = best;
    }
}

// ======== kernel 2: merge+SSE (0..255) + XG (256..511) + assemble ==========
// pd64 visibility across dispatches: kernel-completion release semantics.
__global__ __launch_bounds__(256)
void tail_kernel(const float* __restrict__ H, const float* __restrict__ M,
                 const float* __restrict__ Hdec, const float* __restrict__ W,
                 const float* __restrict__ X, const float* __restrict__ w_d,
                 const unsigned long long* __restrict__ pd64,
                 float* __restrict__ zws, float* __restrict__ out) {
    __shared__ __align__(16) char smem[37376];
    float* accum = zws;
    unsigned int* gcnt = (unsigned int*)(zws + 8);
    float* gcopy = zws + GC_OFF;
    const int tid = threadIdx.x;

    if (blockIdx.x < 256) {
        // ---------------- chunk-merge + memory-loss SSE ----------------
        const int bx = blockIdx.x & 31;      // pos-block
        const int by = blockIdx.x >> 5;      // d-slice 0..7
        const int pos = bx * 256 + tid;
        const int b = pos >> 10;
        const int t = pos & 1023;

        unsigned long long best = ~0ull;
#pragma unroll
        for (int p = 0; p < NKT; ++p) {
            const unsigned long long w = pd64[p * N_POS + pos];
            if (w < best) best = w;
        }
        const int bi = (int)(unsigned int)(best & 0xffffffffu);

        const int d0 = by * 16;
        const float* Hb = H + (b << 17) + t + (d0 << 10);
        const float* Mc = M + (size_t)d0 * K_DIM + bi;   // column gather (L2)
        float s0 = 0.f, s1 = 0.f, s2 = 0.f, s3 = 0.f;
#pragma unroll
        for (int d = 0; d < 16; d += 4) {
            const float e0 = Hb[(d)     << 10] - Mc[(size_t)(d)     * K_DIM];
            const float e1 = Hb[(d + 1) << 10] - Mc[(size_t)(d + 1) * K_DIM];
            const float e2 = Hb[(d + 2) << 10] - Mc[(size_t)(d + 2) * K_DIM];
            const float e3 = Hb[(d + 3) << 10] - Mc[(size_t)(d + 3) * K_DIM];
            s0 += e0 * e0; s1 += e1 * e1; s2 += e2 * e2; s3 += e3 * e3;
        }
        const float r = block_reduce_256((s0 + s1) + (s2 + s3));
        if (tid == 0) atomicAdd(accum + 2, r);
    } else {
        // ------- XG: xhat + E(LDS) + loss_rec/disc + grec partials ----------
        float* Wl = (float*)smem;                // [32][260]
        float* El = Wl + C_DIM * 260;            // [32][32]
        const int xb  = blockIdx.x - 256;        // 0..255
        const int bt0 = xb << 5;

#pragma unroll
        for (int it = 0; it < 8; ++it) {         // stage W
            const int i = it * 1024 + tid * 4;
            const float4 v = *(const float4*)(W + i);
            *(float4*)(Wl + (i >> 8) * 260 + (i & 255)) = v;
        }
        __syncthreads();

        const int c  = tid & 31;
        const int rg = tid >> 5;                 // 0..7
        const int r0 = bt0 + rg, r1 = r0 + 8, r2 = r0 + 16, r3 = r0 + 24;

        float a0 = 0.f, a1 = 0.f, a2 = 0.f, a3 = 0.f;
#pragma unroll 4
        for (int f0 = 0; f0 < F_DIM; f0 += 4) {
            const float4 w4 = *(const float4*)(Wl + c * 260 + f0);
            const float4 h0 = *(const float4*)(Hdec + (size_t)r0 * F_DIM + f0);
            const float4 h1 = *(const float4*)(Hdec + (size_t)r1 * F_DIM + f0);
            const float4 h2 = *(const float4*)(Hdec + (size_t)r2 * F_DIM + f0);
            const float4 h3 = *(const float4*)(Hdec + (size_t)r3 * F_DIM + f0);
            a0 += h0.x * w4.x + h0.y * w4.y + h0.z * w4.z + h0.w * w4.w;
            a1 += h1.x * w4.x + h1.y * w4.y + h1.z * w4.z + h1.w * w4.w;
            a2 += h2.x * w4.x + h2.y * w4.y + h2.z * w4.z + h2.w * w4.w;
            a3 += h3.x * w4.x + h3.y * w4.y + h3.z * w4.z + h3.w * w4.w;
        }

        const float wd = w_d[c];
        const float e0 = a0 - X[(size_t)r0 * C_DIM + c];
        const float e1 = a1 - X[(size_t)r1 * C_DIM + c];
        const float e2 = a2 - X[(size_t)r2 * C_DIM + c];
        const float e3 = a3 - X[(size_t)r3 * C_DIM + c];
        El[(rg)      * C_DIM + c] = e0;
        El[(rg + 8)  * C_DIM + c] = e1;
        El[(rg + 16) * C_DIM + c] = e2;
        El[(rg + 24) * C_DIM + c] = e3;
        const float sse = e0 * e0 + e1 * e1 + e2 * e2 + e3 * e3;
        const float dp  = (a0 + a1 + a2 + a3) * wd;
        const float rA = block_reduce_256(sse);
        if (tid == 0) atomicAdd(accum + 0, rA);
        const float rB = block_reduce_256(dp);
        if (tid == 0) atomicAdd(accum + 1, rB);
        __syncthreads();                         // El fully visible

        // grec in TWO c-halves with gacc[16] (bounded register demand)
        float* gc = gcopy + (size_t)(xb & (NCOPY - 1)) * GCOLS;
        float sf = 0.f;
#pragma unroll
        for (int half = 0; half < 2; ++half) {
            float gacc[16];
#pragma unroll
            for (int cc = 0; cc < 16; ++cc) gacc[cc] = 0.f;
#pragma unroll 1
            for (int i = 0; i < 32; ++i) {
                const float hd = Hdec[(size_t)(bt0 + i) * F_DIM + tid]; // coalesced
                if (half == 0) sf += hd;
#pragma unroll
                for (int c4 = 0; c4 < 4; ++c4) {
                    const float4 e4 =
                        *(const float4*)(El + i * C_DIM + half * 16 + c4 * 4);
                    gacc[c4 * 4 + 0] += e4.x * hd;
                    gacc[c4 * 4 + 1] += e4.y * hd;
                    gacc[c4 * 4 + 2] += e4.z * hd;
                    gacc[c4 * 4 + 3] += e4.w * hd;
                }
            }
#pragma unroll 1
            for (int cc = 0; cc < 16; ++cc)
                atomicAdd(&gc[(half * 16 + cc) * F_DIM + tid], gacc[cc]);
        }
        atomicAdd(&gc[8192 + tid], sf);
    }

    // ============== last block assembles the scalar (R7-proven) ==============
    __shared__ int lastg;
    __threadfence();
    __syncthreads();
    if (tid == 0) lastg = (atomicAdd(gcnt, 1u) == (unsigned)(TAIL_BLOCKS - 1));
    __syncthreads();
    if (lastg) {
        __threadfence();                          // acquire all copies/accum
        float g2 = 0.f;
        for (int i = tid; i < 8192; i += 256) {
            float v = 0.f;
#pragma unroll
            for (int cp = 0; cp < NCOPY; ++cp)
                v += __hip_atomic_load(gcopy + cp * GCOLS + i,
                                       __ATOMIC_RELAXED, __HIP_MEMORY_SCOPE_AGENT);
            g2 += v * v;
        }
        const float rg2 = block_reduce_256(g2);
        float vS = 0.f;
#pragma unroll
        for (int cp = 0; cp < NCOPY; ++cp)
            vS += __hip_atomic_load(gcopy + cp * GCOLS + 8192 + tid,
                                    __ATOMIC_RELAXED, __HIP_MEMORY_SCOPE_AGENT);
        const float rs2 = block_reduce_256(vS * vS);
        float wd2 = (tid < C_DIM) ? w_d[tid] * w_d[tid] : 0.f;
        if (tid < 64) {
#pragma unroll
            for (int off = 32; off > 0; off >>= 1) wd2 += __shfl_down(wd2, off);
        }
        if (tid == 0) {
            const float sse_rec = atomicAdd(accum + 0, 0.f);
            const float dsum    = atomicAdd(accum + 1, 0.f);
            const float sse_mem = atomicAdd(accum + 2, 0.f);
            const float loss_rec = sse_rec / 262144.f;         // /(B*T*C)
            const float loss_d   = -dsum / 8192.f;             // -mean over B*T
            const float loss_m   = 2.f * sse_mem / 1048576.f;  // 2*SSE/(B*D*T)
            const float ngrec    = (2.f / 262144.f) * sqrtf(rg2);
            const float ngd      = sqrtf(wd2 * rs2) / 8192.f;
            const float lmbda    = ngrec / (ngd + 1e-6f);
            out[0] = loss_rec + loss_m + lmbda * loss_d;       // ALPHA = 1
        }
    }
}

// ---------------------------------------------------------------- launcher
extern "C" void kernel_launch(void* const* d_in, const int* in_sizes, int n_in,
                              void* d_out, int out_size, void* d_ws, size_t ws_size,
                              hipStream_t stream) {
    const float* X    = (const float*)d_in[0];   // [8,1024,32]
    const float* H    = (const float*)d_in[1];   // [8,128,1024]
    const float* M    = (const float*)d_in[2];   // [128,512]
    const float* Hdec = (const float*)d_in[3];   // [8,1024,256]
    const float* W    = (const float*)d_in[4];   // [32,256]
    const float* w_d  = (const float*)d_in[5];   // [32]

    float* zws = (float*)d_ws;
    unsigned long long* pd64 = (unsigned long long*)(zws + ZWS_FLOATS); // 8B-aligned

    hipMemsetAsync(zws, 0, ZWS_FLOATS * sizeof(float), stream);
    nn_kernel  <<<NN_BLOCKS,   256, 0, stream>>>(H, M, pd64);
    tail_kernel<<<TAIL_BLOCKS, 256, 0, stream>>>(H, M, Hdec, W, X, w_d,
                                                 pd64, zws, (float*)d_out);
}

// Round 10
// 152.352 us; speedup vs baseline: 1.5074x; 1.1994x over previous
//
#include <hip/hip_runtime.h>
#include <math.h>

// Problem constants (B=8, T=1024, C=32, F=256, D=128, K=512)
#define N_POS 8192
#define D_DIM 128
#define K_DIM 512
#define C_DIM 32
#define F_DIM 256

#define PT 64            // positions per NN tile
#define KW 128           // codewords per NN tile
#define NKT 4            // k-tiles
#define NN_BLOCKS 512    // 128 ptiles x 4 ktiles
#define TAIL_BLOCKS 512  // 256 merge+SSE + 256 XG
#define GREC_COLS 8448   // 32*256 g_rec + 256 S
#define GFIN_BLOCKS 132

// ws layout (floats): [0..15] accum (0=sse_rec,1=dsum,2=sse_mem,3=g2,4=s2,
// [5]=counter as uint) -- memset to 0 each call.  pp [256][8448] partials
// (fully overwritten, no zeroing).  pd64 (u64[4*8192]) follows, 8B-aligned.
#define PP_OFF   16
#define PD_OFF   (PP_OFF + 256 * GREC_COLS)     // 2162704 floats (byte ofs %8==0)

// ---------------------------------------------------------------- reductions
__device__ __forceinline__ float block_reduce_256(float v) {
    __shared__ float sbuf[4];
    __syncthreads();
#pragma unroll
    for (int off = 32; off > 0; off >>= 1) v += __shfl_down(v, off);
    const int lane = threadIdx.x & 63;
    const int w    = threadIdx.x >> 6;
    if (lane == 0) sbuf[w] = v;
    __syncthreads();
    return (threadIdx.x == 0) ? (sbuf[0] + sbuf[1] + sbuf[2] + sbuf[3]) : 0.f;
}

// ============ kernel 1: NN search, DEDICATED (R9-proven, untouched) =========
// 64 pos x 128 k tile, 4x8 acc. Writes packed u64 (dist_bits<<32 | k);
// u64-min == lexicographic (dist, k) == reference first-min tie-break.
__global__ __launch_bounds__(256, 2)
void nn_kernel(const float* __restrict__ H, const float* __restrict__ M,
               unsigned long long* __restrict__ pd64) {
    __shared__ __align__(16) char smem[32768];
    float* hT = (float*)smem;                                   // [32][64]
    float* mT = hT + 2048;                                      // [32][128]
    unsigned long long* red64 = (unsigned long long*)(smem + 24576); // [16][64]
    const int tid = threadIdx.x;

    const int ptile = blockIdx.x >> 2;       // 0..127
    const int ktile = blockIdx.x & 3;        // 0..3
    const int pos0  = ptile * PT;            // 64-aligned, never crosses b
    const int b     = pos0 >> 10;
    const int t0    = pos0 & 1023;
    const int k0    = ktile * KW;
    const float* Hb = H + (b << 17) + t0;

    const int p4 = (tid & 15) << 2;          // pos quad 0..60
    const int q8 = (tid >> 4) << 3;          // k octet 0..120

    float acc[4][8];
#pragma unroll
    for (int i = 0; i < 4; ++i)
#pragma unroll
        for (int j = 0; j < 8; ++j) acc[i][j] = 0.f;

    for (int ch = 0; ch < 4; ++ch) {         // 32-d chunks
        const int d0 = ch << 5;
        __syncthreads();
        {
            int idx = tid * 4;               // hT: 2048 floats
#pragma unroll
            for (int it = 0; it < 2; ++it, idx += 1024) {
                const int d = idx >> 6, cc = idx & 63;
                *(float4*)(hT + idx) =
                    *(const float4*)(Hb + ((size_t)(d0 + d) << 10) + cc);
            }
            idx = tid * 4;                   // mT: 4096 floats
#pragma unroll
            for (int it = 0; it < 4; ++it, idx += 1024) {
                const int d = idx >> 7, cc = idx & 127;
                *(float4*)(mT + idx) =
                    *(const float4*)(M + (size_t)(d0 + d) * K_DIM + k0 + cc);
            }
        }
        __syncthreads();
#pragma unroll 2
        for (int d = 0; d < 32; ++d) {
            const float4 h4 = *(const float4*)(hT + (d << 6) + p4);
            const float4 m0 = *(const float4*)(mT + (d << 7) + q8);
            const float4 m1 = *(const float4*)(mT + (d << 7) + q8 + 4);
            const float hh[4] = {h4.x, h4.y, h4.z, h4.w};
            const float mm[8] = {m0.x, m0.y, m0.z, m0.w, m1.x, m1.y, m1.z, m1.w};
#pragma unroll
            for (int i = 0; i < 4; ++i)
#pragma unroll
                for (int j = 0; j < 8; ++j)
                    acc[i][j] += fabsf(hh[i] - mm[j]);
        }
    }

    // per-thread argmin over 8 ks (j ascending, strict < -> lowest k on tie)
#pragma unroll
    for (int i = 0; i < 4; ++i) {
        float bd = acc[i][0];
        int   bj = 0;
#pragma unroll
        for (int j = 1; j < 8; ++j)
            if (acc[i][j] < bd) { bd = acc[i][j]; bj = j; }
        red64[(tid >> 4) * PT + p4 + i] =
            ((unsigned long long)__float_as_uint(bd) << 32)
            | (unsigned int)(k0 + q8 + bj);
    }
    __syncthreads();
    if (tid < PT) {
        unsigned long long best = red64[tid];
#pragma unroll
        for (int g = 1; g < 16; ++g) {
            const unsigned long long w = red64[g * PT + tid];
            if (w < best) best = w;
        }
        pd64[ktile * N_POS + pos0 + tid] = best;
    }
}

// ======== kernel 2: merge+SSE (0..255) + XG with partial STORES (256..511) ==
// NO bulk atomics: XG exports its 8448-float partial via coalesced stores
// (R9's 2.1M device-scope atomicAdds were memory-side serialized -> 73 us).
__global__ __launch_bounds__(256)
void tail_kernel(const float* __restrict__ H, const float* __restrict__ M,
                 const float* __restrict__ Hdec, const float* __restrict__ W,
                 const float* __restrict__ X, const float* __restrict__ w_d,
                 const unsigned long long* __restrict__ pd64,
                 float* __restrict__ accum, float* __restrict__ pp) {
    __shared__ __align__(16) char smem[37376];
    const int tid = threadIdx.x;

    if (blockIdx.x < 256) {
        // ---------------- chunk-merge + memory-loss SSE ----------------
        const int bx = blockIdx.x & 31;      // pos-block
        const int by = blockIdx.x >> 5;      // d-slice 0..7
        const int pos = bx * 256 + tid;
        const int b = pos >> 10;
        const int t = pos & 1023;

        unsigned long long best = ~0ull;
#pragma unroll
        for (int p = 0; p < NKT; ++p) {
            const unsigned long long w = pd64[p * N_POS + pos];
            if (w < best) best = w;
        }
        const int bi = (int)(unsigned int)(best & 0xffffffffu);

        const int d0 = by * 16;
        const float* Hb = H + (b << 17) + t + (d0 << 10);
        const float* Mc = M + (size_t)d0 * K_DIM + bi;   // column gather (L2)
        float s0 = 0.f, s1 = 0.f, s2 = 0.f, s3 = 0.f;
#pragma unroll
        for (int d = 0; d < 16; d += 4) {
            const float e0 = Hb[(d)     << 10] - Mc[(size_t)(d)     * K_DIM];
            const float e1 = Hb[(d + 1) << 10] - Mc[(size_t)(d + 1) * K_DIM];
            const float e2 = Hb[(d + 2) << 10] - Mc[(size_t)(d + 2) * K_DIM];
            const float e3 = Hb[(d + 3) << 10] - Mc[(size_t)(d + 3) * K_DIM];
            s0 += e0 * e0; s1 += e1 * e1; s2 += e2 * e2; s3 += e3 * e3;
        }
        const float r = block_reduce_256((s0 + s1) + (s2 + s3));
        if (tid == 0) atomicAdd(accum + 2, r);
    } else {
        // ------- XG: xhat + E(LDS) + loss_rec/disc + grec partial stores -----
        float* Wl = (float*)smem;                // [32][260]
        float* El = Wl + C_DIM * 260;            // [32][32]
        const int xb  = blockIdx.x - 256;        // 0..255
        const int bt0 = xb << 5;

#pragma unroll
        for (int it = 0; it < 8; ++it) {         // stage W
            const int i = it * 1024 + tid * 4;
            const float4 v = *(const float4*)(W + i);
            *(float4*)(Wl + (i >> 8) * 260 + (i & 255)) = v;
        }
        __syncthreads();

        const int c  = tid & 31;
        const int rg = tid >> 5;                 // 0..7
        const int r0 = bt0 + rg, r1 = r0 + 8, r2 = r0 + 16, r3 = r0 + 24;

        float a0 = 0.f, a1 = 0.f, a2 = 0.f, a3 = 0.f;
#pragma unroll 4
        for (int f0 = 0; f0 < F_DIM; f0 += 4) {
            const float4 w4 = *(const float4*)(Wl + c * 260 + f0);
            const float4 h0 = *(const float4*)(Hdec + (size_t)r0 * F_DIM + f0);
            const float4 h1 = *(const float4*)(Hdec + (size_t)r1 * F_DIM + f0);
            const float4 h2 = *(const float4*)(Hdec + (size_t)r2 * F_DIM + f0);
            const float4 h3 = *(const float4*)(Hdec + (size_t)r3 * F_DIM + f0);
            a0 += h0.x * w4.x + h0.y * w4.y + h0.z * w4.z + h0.w * w4.w;
            a1 += h1.x * w4.x + h1.y * w4.y + h1.z * w4.z + h1.w * w4.w;
            a2 += h2.x * w4.x + h2.y * w4.y + h2.z * w4.z + h2.w * w4.w;
            a3 += h3.x * w4.x + h3.y * w4.y + h3.z * w4.z + h3.w * w4.w;
        }

        const float wd = w_d[c];
        const float e0 = a0 - X[(size_t)r0 * C_DIM + c];
        const float e1 = a1 - X[(size_t)r1 * C_DIM + c];
        const float e2 = a2 - X[(size_t)r2 * C_DIM + c];
        const float e3 = a3 - X[(size_t)r3 * C_DIM + c];
        El[(rg)      * C_DIM + c] = e0;
        El[(rg + 8)  * C_DIM + c] = e1;
        El[(rg + 16) * C_DIM + c] = e2;
        El[(rg + 24) * C_DIM + c] = e3;
        const float sse = e0 * e0 + e1 * e1 + e2 * e2 + e3 * e3;
        const float dp  = (a0 + a1 + a2 + a3) * wd;
        const float rA = block_reduce_256(sse);
        if (tid == 0) atomicAdd(accum + 0, rA);
        const float rB = block_reduce_256(dp);
        if (tid == 0) atomicAdd(accum + 1, rB);
        __syncthreads();                         // El fully visible

        // grec in TWO c-halves with gacc[16]; export via plain stores
        float* o = pp + (size_t)xb * GREC_COLS;
        float sf = 0.f;
#pragma unroll
        for (int half = 0; half < 2; ++half) {
            float gacc[16];
#pragma unroll
            for (int cc = 0; cc < 16; ++cc) gacc[cc] = 0.f;
#pragma unroll 1
            for (int i = 0; i < 32; ++i) {
                const float hd = Hdec[(size_t)(bt0 + i) * F_DIM + tid]; // coalesced
                if (half == 0) sf += hd;
#pragma unroll
                for (int c4 = 0; c4 < 4; ++c4) {
                    const float4 e4 =
                        *(const float4*)(El + i * C_DIM + half * 16 + c4 * 4);
                    gacc[c4 * 4 + 0] += e4.x * hd;
                    gacc[c4 * 4 + 1] += e4.y * hd;
                    gacc[c4 * 4 + 2] += e4.z * hd;
                    gacc[c4 * 4 + 3] += e4.w * hd;
                }
            }
#pragma unroll 1
            for (int cc = 0; cc < 16; ++cc)
                o[(half * 16 + cc) * F_DIM + tid] = gacc[cc];   // coalesced store
        }
        o[8192 + tid] = sf;
    }
}

// ==== kernel 3: reduce partials -> norms; last block assembles the scalar ====
// grid 132 x 256 (R4-proven). Blocks 0..127 -> g_rec^2 (accum[3]);
// 128..131 -> S^2 (accum[4]). Counter-based last-block assemble.
__global__ __launch_bounds__(256)
void grec_final(const float* __restrict__ pp, const float* __restrict__ w_d,
                float* __restrict__ accum, float* __restrict__ out) {
    const int tid = threadIdx.x;
    const int col = blockIdx.x * 64 + (tid & 63);
    const int pc  = tid >> 6;                  // 0..3
    const float* base = pp + (size_t)(pc * 64) * GREC_COLS + col;
    float s = 0.f;
#pragma unroll 8
    for (int p = 0; p < 64; ++p) s += base[(size_t)p * GREC_COLS];
    __shared__ float red[4][64];
    red[pc][tid & 63] = s;
    __syncthreads();
    if (tid < 64) {
        const float tot = red[0][tid] + red[1][tid] + red[2][tid] + red[3][tid];
        float v = tot * tot;
#pragma unroll
        for (int off = 32; off > 0; off >>= 1) v += __shfl_down(v, off);
        if (tid == 0)
            atomicAdd(accum + ((blockIdx.x >= 128) ? 4 : 3), v);
    }

    // ---- last block to finish assembles the scalar ----
    __shared__ int is_last;
    if (tid == 0) {
        __threadfence();
        unsigned int* cnt = (unsigned int*)(accum + 5);
        is_last = (atomicAdd(cnt, 1u) == GFIN_BLOCKS - 1);
    }
    __syncthreads();
    if (is_last && tid < 64) {
        float wd2 = (tid < C_DIM) ? w_d[tid] * w_d[tid] : 0.f;
#pragma unroll
        for (int off = 32; off > 0; off >>= 1) wd2 += __shfl_down(wd2, off);
        if (tid == 0) {
            __threadfence();
            const float sse_rec = atomicAdd(accum + 0, 0.f);
            const float dsum    = atomicAdd(accum + 1, 0.f);
            const float sse_mem = atomicAdd(accum + 2, 0.f);
            const float g2      = atomicAdd(accum + 3, 0.f);
            const float s2      = atomicAdd(accum + 4, 0.f);
            const float loss_rec = sse_rec / 262144.f;         // /(B*T*C)
            const float loss_d   = -dsum / 8192.f;             // -mean over B*T
            const float loss_m   = 2.f * sse_mem / 1048576.f;  // 2*SSE/(B*D*T)
            const float ngrec    = (2.f / 262144.f) * sqrtf(g2);
            const float ngd      = sqrtf(wd2 * s2) / 8192.f;
            const float lmbda    = ngrec / (ngd + 1e-6f);
            out[0] = loss_rec + loss_m + lmbda * loss_d;       // ALPHA = 1
        }
    }
}

// ---------------------------------------------------------------- launcher
extern "C" void kernel_launch(void* const* d_in, const int* in_sizes, int n_in,
                              void* d_out, int out_size, void* d_ws, size_t ws_size,
                              hipStream_t stream) {
    const float* X    = (const float*)d_in[0];   // [8,1024,32]
    const float* H    = (const float*)d_in[1];   // [8,128,1024]
    const float* M    = (const float*)d_in[2];   // [128,512]
    const float* Hdec = (const float*)d_in[3];   // [8,1024,256]
    const float* W    = (const float*)d_in[4];   // [32,256]
    const float* w_d  = (const float*)d_in[5];   // [32]

    float* ws    = (float*)d_ws;
    float* accum = ws;                               // 16 floats
    float* pp    = ws + PP_OFF;                      // 256*8448
    unsigned long long* pd64 = (unsigned long long*)(ws + PD_OFF);

    hipMemsetAsync(accum, 0, 16 * sizeof(float), stream);
    nn_kernel  <<<NN_BLOCKS,   256, 0, stream>>>(H, M, pd64);
    tail_kernel<<<TAIL_BLOCKS, 256, 0, stream>>>(H, M, Hdec, W, X, w_d,
                                                 pd64, accum, pp);
    grec_final <<<GFIN_BLOCKS, 256, 0, stream>>>(pp, w_d, accum, (float*)d_out);
}